// Round 3
// baseline (181.023 us; speedup 1.0000x reference)
//
#include <hip/hip_runtime.h>
#include <hip/hip_bf16.h>

// SparseProtoLinear: S=131072 tokens, D=64, P=8 experts.
// d_out = [y (S*64) | logits (S*8) | mask (S*8)], fp32.
//
// prep_w: fp32 W1/W2 -> bf16, pre-swizzled 128KB LDS image in d_ws.
// spl_main: 256 blocks x 512 thr (8 waves = 1 CU), LDS = whole W image.
//   Per wave: 32 tokens/tile, 2 tiles. Zero barriers after prologue.
//   GEMM1 swapped (D1 = W1 x X^T via mfma_16x16x32): C-layout == B-frag
//   layout of mfma_16x16x16 -> silu output feeds GEMM2 entirely in-register.

typedef __attribute__((ext_vector_type(8))) short short8;
typedef __attribute__((ext_vector_type(4))) short bf16x4;   // renamed: HIP owns `short4`
typedef __attribute__((ext_vector_type(4))) float f32x4;
typedef __attribute__((ext_vector_type(4))) unsigned int u32x4;
typedef __attribute__((ext_vector_type(2))) unsigned int u32x2;

#define NEXP 8
#define DH 64

__device__ __forceinline__ unsigned int f2bf(float f) {
    unsigned int u = __builtin_bit_cast(unsigned int, f);
    return (u + 0x7fffu + ((u >> 16) & 1u)) >> 16;  // RTNE
}

#if __has_builtin(__builtin_amdgcn_mfma_f32_16x16x16_bf16)
#define MFMA16(a, b, c) __builtin_amdgcn_mfma_f32_16x16x16_bf16(a, b, c, 0, 0, 0)
#elif __has_builtin(__builtin_amdgcn_mfma_f32_16x16x16bf16_1k)
#define MFMA16(a, b, c) __builtin_amdgcn_mfma_f32_16x16x16bf16_1k(a, b, c, 0, 0, 0)
#else
__device__ __forceinline__ f32x4 mfma16_asm(bf16x4 a, bf16x4 b, f32x4 c) {
    asm volatile("v_mfma_f32_16x16x16_bf16 %0, %1, %2, %0\n\ts_nop 7\n\ts_nop 2"
                 : "+v"(c) : "v"(a), "v"(b));
    return c;
}
#define MFMA16(a, b, c) mfma16_asm(a, b, c)
#endif

// ---------------- prep: weights -> bf16 swizzled image ----------------
__global__ void prep_w(const float* __restrict__ w1, const float* __restrict__ w2,
                       unsigned char* __restrict__ ws) {
    int q = blockIdx.x * 256 + threadIdx.x;          // 16384 f32x4-quads
    int mat = q >> 13;                               // 0=W1, 1=W2
    int p = (q >> 10) & 7;
    int o = (q >> 4) & 63;                           // row (o for W1, d for W2)
    int dq = q & 15;                                 // col quad (4 f32)
    const float* src = (mat ? w2 : w1) + (((p << 6) + o) << 6) + (dq << 2);
    f32x4 v = *reinterpret_cast<const f32x4*>(src);
    u32x2 pk;
    pk[0] = f2bf(v[0]) | (f2bf(v[1]) << 16);
    pk[1] = f2bf(v[2]) | (f2bf(v[3]) << 16);
    // image byte: expert base + mat + row*128 + (colbyte ^ (row&7)<<4)
    int off = (p << 14) + (mat << 13) + (o << 7) + ((dq << 3) ^ ((o & 7) << 4));
    *reinterpret_cast<u32x2*>(ws + off) = pk;
}

// ---------------- main fused kernel ----------------
__global__ __launch_bounds__(512, 1)
void spl_main(const float* __restrict__ x, const float* __restrict__ proto,
              const float* __restrict__ gate, const unsigned char* __restrict__ wimg,
              float* __restrict__ y_out, float* __restrict__ logits_out,
              float* __restrict__ mask_out)
{
    extern __shared__ char smem[];                   // 131072 B: 8 experts x (W1 8K | W2 8K)
    const int tid = threadIdx.x;
    const int lane = tid & 63;
    const int wv = tid >> 6;                         // wave 0..7
    const int fr = lane & 15;
    const int fg = (lane >> 4) & 3;
    const int sw = (fr & 7) << 4;                    // XOR swizzle (row&7 == fr&7)

    // ---- stage W image -> LDS (linear copy; image pre-swizzled) ----
    {
        const u32x4* src = reinterpret_cast<const u32x4*>(wimg);
        u32x4* dst = reinterpret_cast<u32x4*>(smem);
#pragma unroll
        for (int it = 0; it < 16; ++it) {
            int idx = it * 512 + tid;
            dst[idx] = src[idx];
        }
    }

    const int tbase = blockIdx.x * 512 + wv * 32;

    float xA[2][2][8], xB[2][2][8];
    auto loadX = [&](float (&xv)[2][2][8], int t0) {
#pragma unroll
        for (int n = 0; n < 2; ++n)
#pragma unroll
            for (int kk = 0; kk < 2; ++kk) {
                const float* g = x + (size_t)(t0 + n * 16 + fr) * DH + kk * 32 + fg * 8;
                f32x4 a = *reinterpret_cast<const f32x4*>(g);
                f32x4 b = *reinterpret_cast<const f32x4*>(g + 4);
#pragma unroll
                for (int i = 0; i < 4; ++i) { xv[n][kk][i] = a[i]; xv[n][kk][4 + i] = b[i]; }
            }
    };

    auto do_tile = [&](float (&xv)[2][2][8], int t0) {
        // ---- logits / mask / weights (fp32) ----
        float wtv[2][NEXP];
        {
            float dot[2][NEXP];
#pragma unroll
            for (int n = 0; n < 2; ++n)
#pragma unroll
                for (int p = 0; p < NEXP; ++p) dot[n][p] = 0.f;
#pragma unroll
            for (int p = 0; p < NEXP; ++p)
#pragma unroll
                for (int kk = 0; kk < 2; ++kk) {
                    const float* pr = proto + p * DH + kk * 32 + fg * 8;
                    f32x4 p0 = *reinterpret_cast<const f32x4*>(pr);
                    f32x4 p1 = *reinterpret_cast<const f32x4*>(pr + 4);
#pragma unroll
                    for (int n = 0; n < 2; ++n)
#pragma unroll
                        for (int i = 0; i < 4; ++i)
                            dot[n][p] += xv[n][kk][i] * p0[i] + xv[n][kk][4 + i] * p1[i];
                }
            float lg[2][NEXP], mk[2][NEXP];
#pragma unroll
            for (int n = 0; n < 2; ++n)
#pragma unroll
                for (int p = 0; p < NEXP; ++p) {
                    float v = dot[n][p];
                    v += __shfl_xor(v, 16);          // 4-lane butterfly over fg
                    v += __shfl_xor(v, 32);
                    float l = v * 0.125f - gate[p];  // /sqrt(64)
                    float m = fmaxf(l, 0.f);
                    lg[n][p] = l; mk[n][p] = m;
                    wtv[n][p] = (m > 1e-6f) ? m : 0.f;
                }
            // fg0: logits n=0, fg1: logits n=1, fg2: mask n=0, fg3: mask n=1
            int ns = fg & 1;
            size_t rowb = (size_t)(t0 + ns * 16 + fr) * NEXP;
            f32x4 v0, v1;
            if (fg < 2) {
#pragma unroll
                for (int i = 0; i < 4; ++i) { v0[i] = lg[ns][i]; v1[i] = lg[ns][4 + i]; }
                *reinterpret_cast<f32x4*>(logits_out + rowb) = v0;
                *reinterpret_cast<f32x4*>(logits_out + rowb + 4) = v1;
            } else {
#pragma unroll
                for (int i = 0; i < 4; ++i) { v0[i] = mk[ns][i]; v1[i] = mk[ns][4 + i]; }
                *reinterpret_cast<f32x4*>(mask_out + rowb) = v0;
                *reinterpret_cast<f32x4*>(mask_out + rowb + 4) = v1;
            }
        }
        // ---- X -> bf16 B-fragments ----
        short8 xb[2][2];
#pragma unroll
        for (int n = 0; n < 2; ++n)
#pragma unroll
            for (int kk = 0; kk < 2; ++kk) {
                short8 t;
#pragma unroll
                for (int j = 0; j < 8; ++j) t[j] = (short)f2bf(xv[n][kk][j]);
                xb[n][kk] = t;
            }
        // ---- expert loop: zero barriers ----
        f32x4 yacc[4][2];
#pragma unroll
        for (int mt = 0; mt < 4; ++mt)
#pragma unroll
            for (int n = 0; n < 2; ++n) yacc[mt][n] = (f32x4){0.f, 0.f, 0.f, 0.f};

#pragma unroll
        for (int p = 0; p < NEXP; ++p) {
            const int eb = p << 14;
            // GEMM1: D1[o][t] = W1 x X^T  (A=W1 frags, B=xb)
            short8 w1f[4][2];
#pragma unroll
            for (int mt = 0; mt < 4; ++mt)
#pragma unroll
                for (int kk = 0; kk < 2; ++kk)
                    w1f[mt][kk] = *reinterpret_cast<const short8*>(
                        smem + eb + (mt * 16 + fr) * 128 + ((kk * 64 + fg * 16) ^ sw));
            f32x4 acc1[4][2];
#pragma unroll
            for (int mt = 0; mt < 4; ++mt)
#pragma unroll
                for (int n = 0; n < 2; ++n) acc1[mt][n] = (f32x4){0.f, 0.f, 0.f, 0.f};
#pragma unroll
            for (int kk = 0; kk < 2; ++kk)
#pragma unroll
                for (int mt = 0; mt < 4; ++mt)
#pragma unroll
                    for (int n = 0; n < 2; ++n)
                        acc1[mt][n] = __builtin_amdgcn_mfma_f32_16x16x32_bf16(
                            w1f[mt][kk], xb[n][kk], acc1[mt][n], 0, 0, 0);
            // silu -> bf16: C-layout (o=fg*4+r, t=fr) == mfma16 B-frag layout
            bf16x4 pkB[4][2];
#pragma unroll
            for (int mt = 0; mt < 4; ++mt)
#pragma unroll
                for (int n = 0; n < 2; ++n) {
                    bf16x4 t;
#pragma unroll
                    for (int r = 0; r < 4; ++r) {
                        float h = acc1[mt][n][r];
                        float s = h * __builtin_amdgcn_rcpf(1.f + __expf(-h));
                        t[r] = (short)f2bf(s);
                    }
                    pkB[mt][n] = t;
                }
            // GEMM2: Out^T[d][t] = W2 x Hmid^T  (A=W2 frags, B=pkB), K=16 slices
            bf16x4 w2f[4][4];
#pragma unroll
            for (int mt = 0; mt < 4; ++mt)
#pragma unroll
                for (int mp = 0; mp < 4; ++mp)
                    w2f[mt][mp] = *reinterpret_cast<const bf16x4*>(
                        smem + eb + 8192 + (mt * 16 + fr) * 128 + ((mp * 32 + fg * 8) ^ sw));
            f32x4 acc2[4][2];
#pragma unroll
            for (int mt = 0; mt < 4; ++mt)
#pragma unroll
                for (int n = 0; n < 2; ++n) acc2[mt][n] = (f32x4){0.f, 0.f, 0.f, 0.f};
#pragma unroll
            for (int mp = 0; mp < 4; ++mp)
#pragma unroll
                for (int mt = 0; mt < 4; ++mt)
#pragma unroll
                    for (int n = 0; n < 2; ++n)
                        acc2[mt][n] = MFMA16(w2f[mt][mp], pkB[mp][n], acc2[mt][n]);
            // weighted combine (wt is a per-lane register)
#pragma unroll
            for (int mt = 0; mt < 4; ++mt)
#pragma unroll
                for (int n = 0; n < 2; ++n)
#pragma unroll
                    for (int r = 0; r < 4; ++r)
                        yacc[mt][n][r] += wtv[n][p] * acc2[mt][n][r];
        }
        // ---- y store: Out^T lane (d=mt*16+fg*4+r, t=n*16+fr) -> f32x4 ----
#pragma unroll
        for (int mt = 0; mt < 4; ++mt)
#pragma unroll
            for (int n = 0; n < 2; ++n) {
                f32x4 v;
#pragma unroll
                for (int r = 0; r < 4; ++r) v[r] = yacc[mt][n][r];
                *reinterpret_cast<f32x4*>(
                    y_out + (size_t)(t0 + n * 16 + fr) * DH + mt * 16 + fg * 4) = v;
            }
    };

    loadX(xA, tbase);
    __syncthreads();               // W image visible; only barrier in the kernel
    loadX(xB, tbase + 256);        // prefetch tile 1 under tile 0 compute
    do_tile(xA, tbase);
    do_tile(xB, tbase + 256);
}

extern "C" void kernel_launch(void* const* d_in, const int* in_sizes, int n_in,
                              void* d_out, int out_size, void* d_ws, size_t ws_size,
                              hipStream_t stream) {
    (void)n_in; (void)out_size; (void)ws_size;
    const float* x     = (const float*)d_in[0];
    const float* proto = (const float*)d_in[1];
    const float* gate  = (const float*)d_in[2];
    const float* w1    = (const float*)d_in[3];
    const float* w2    = (const float*)d_in[4];
    float* y = (float*)d_out;
    const int S = in_sizes[0] / DH;                  // 131072
    float* logits = y + (size_t)S * DH;
    float* mask   = logits + (size_t)S * NEXP;
    unsigned char* wimg = (unsigned char*)d_ws;      // 128 KiB

    prep_w<<<64, 256, 0, stream>>>(w1, w2, wimg);

    (void)hipFuncSetAttribute(reinterpret_cast<const void*>(spl_main),
                              hipFuncAttributeMaxDynamicSharedMemorySize, 131072);
    spl_main<<<S / 512, 512, 131072, stream>>>(x, proto, gate, wimg, y, logits, mask);
}

// Round 5
// 57.898 us; speedup vs baseline: 3.1266x; 3.1266x over previous
//
#include <hip/hip_runtime.h>
#include <hip/hip_bf16.h>

// SparseProtoLinear: S=131072 tokens, D=64, P=8 experts.
// d_out = [y (S*64) | logits (S*8) | mask (S*8)], fp32.
//
// prep_w: fp32 W1/W2 -> bf16 image in d_ws (XOR-swizzled rows; W2 columns
//         permuted [mp|fg|j]->[fg|mp|j] so GEMM2 A-frags read as b128).
// spl_main: 1024 blocks x 256 thr (4 waves), 128 tokens/block, 32/wave.
//   Phase A (no DMA in flight): X->reg, fp32 logits/mask/wt (+4KB LDS wt
//   table), stores. Phase B: W double-buffered via global_load_lds, expert
//   loop (unroll 1, 1 barrier/expert): GEMM1 swapped (W1 x X^T, 16x16x32),
//   silu*wt packed in-register -> GEMM2 (16x16x16) accumulates into yacc.

typedef __attribute__((ext_vector_type(8))) short short8;
typedef __attribute__((ext_vector_type(4))) short bf16x4;   // HIP owns `short4`
typedef __attribute__((ext_vector_type(4))) float f32x4;
typedef __attribute__((ext_vector_type(4))) unsigned int u32x4;
typedef __attribute__((ext_vector_type(2))) unsigned int u32x2;

#define NEXP 8
#define DH 64
#define BT 128
#define THREADS 256
#define OFF_WT 32768
#define LDS_BYTES 36864

__device__ __forceinline__ unsigned int f2bf(float f) {
    unsigned int u = __builtin_bit_cast(unsigned int, f);
    return (u + 0x7fffu + ((u >> 16) & 1u)) >> 16;  // RTNE
}

#if __has_builtin(__builtin_amdgcn_mfma_f32_16x16x16_bf16)
#define MFMA16(a, b, c) __builtin_amdgcn_mfma_f32_16x16x16_bf16(a, b, c, 0, 0, 0)
#else
#define MFMA16(a, b, c) __builtin_amdgcn_mfma_f32_16x16x16bf16_1k(a, b, c, 0, 0, 0)
#endif

typedef const unsigned int __attribute__((address_space(1)))* gas_u32p;
typedef unsigned int __attribute__((address_space(3)))* las_u32p;

// g includes the per-lane offset; lbase is wave-uniform (HW adds lane*16).
__device__ __forceinline__ void glds16(const void* g, void* lbase, int lane) {
#if __has_builtin(__builtin_amdgcn_global_load_lds)
    (void)lane;
    __builtin_amdgcn_global_load_lds((gas_u32p)g, (las_u32p)lbase, 16, 0, 0);
#else
    *reinterpret_cast<u32x4*>(reinterpret_cast<char*>(lbase) + lane * 16) =
        *reinterpret_cast<const u32x4*>(g);
#endif
}

// ---------------- prep: weights -> bf16 swizzled image (128 KiB) ----------------
__global__ void prep_w(const float* __restrict__ w1, const float* __restrict__ w2,
                       unsigned char* __restrict__ ws) {
    int q = blockIdx.x * 256 + threadIdx.x;          // 16384 quads of 4 f32
    int mat = q >> 13;                               // 0=W1, 1=W2
    int p = (q >> 10) & 7;
    int r = (q >> 4) & 63;                           // source row (o for W1, d for W2)
    int dq = q & 15;                                 // source col quad
    const float* src = (mat ? w2 : w1) + (size_t)(((p << 6) + r) << 6) + (dq << 2);
    f32x4 v = *reinterpret_cast<const f32x4*>(src);
    u32x2 pk;
    pk[0] = f2bf(v[0]) | (f2bf(v[1]) << 16);
    pk[1] = f2bf(v[2]) | (f2bf(v[3]) << 16);
    // W1: byte col = dq*8.  W2 col-permute o=[mp|fg|j]->[fg|mp|j]:
    //   mp=dq>>2, fg=dq&3 -> byte col = fg*32 + mp*8.
    int col = mat ? (((dq & 3) << 5) | ((dq >> 2) << 3)) : (dq << 3);
    int off = (p << 14) + (mat << 13) + (r << 7) + (col ^ ((r & 7) << 4));
    *reinterpret_cast<u32x2*>(ws + off) = pk;
}

// ---------------- main fused kernel ----------------
__global__ __launch_bounds__(THREADS, 3)
void spl_main(const float* __restrict__ x, const float* __restrict__ proto,
              const float* __restrict__ gate, const unsigned char* __restrict__ wimg,
              float* __restrict__ y_out, float* __restrict__ logits_out,
              float* __restrict__ mask_out)
{
    __shared__ __align__(16) char smem[LDS_BYTES];   // [0,32K) W dbuf | [32K,36K) wt
    const int tid = threadIdx.x;
    const int lane = tid & 63;
    const int wv = __builtin_amdgcn_readfirstlane(tid >> 6);
    const int fr = lane & 15;
    const int fg = (lane >> 4) & 3;
    const int sw = (fr & 7) << 4;
    const int t0 = blockIdx.x * BT + wv * 32;

    // stage expert p's 16KB into buffer b (4 waves x 4 chunks of 1KB)
    auto stage = [&](int p, int b) {
#pragma unroll
        for (int i = 0; i < 4; ++i) {
            const int ch = (i * 4 + wv) << 10;
            glds16(wimg + (p << 14) + ch + lane * 16, smem + (b << 14) + ch, lane);
        }
    };

    // ---- Phase A: X load + logits/mask/wt (NO DMA in flight) ----
    float xv[2][2][8];
#pragma unroll
    for (int n = 0; n < 2; ++n)
#pragma unroll
        for (int kk = 0; kk < 2; ++kk) {
            const float* g = x + (size_t)(t0 + n * 16 + fr) * DH + kk * 32 + fg * 8;
            f32x4 a = *reinterpret_cast<const f32x4*>(g);
            f32x4 b = *reinterpret_cast<const f32x4*>(g + 4);
#pragma unroll
            for (int i = 0; i < 4; ++i) { xv[n][kk][i] = a[i]; xv[n][kk][4 + i] = b[i]; }
        }
    {
        float dot[2][NEXP];
#pragma unroll
        for (int n = 0; n < 2; ++n)
#pragma unroll
            for (int p = 0; p < NEXP; ++p) dot[n][p] = 0.f;
#pragma unroll
        for (int p = 0; p < NEXP; ++p)
#pragma unroll
            for (int kk = 0; kk < 2; ++kk) {
                const float* pr = proto + p * DH + kk * 32 + fg * 8;
                f32x4 p0 = *reinterpret_cast<const f32x4*>(pr);
                f32x4 p1 = *reinterpret_cast<const f32x4*>(pr + 4);
#pragma unroll
                for (int n = 0; n < 2; ++n)
#pragma unroll
                    for (int i = 0; i < 4; ++i)
                        dot[n][p] += xv[n][kk][i] * p0[i] + xv[n][kk][4 + i] * p1[i];
            }
        float lg[2][NEXP], mk[2][NEXP];
#pragma unroll
        for (int n = 0; n < 2; ++n)
#pragma unroll
            for (int p = 0; p < NEXP; ++p) {
                float v = dot[n][p];
                v += __shfl_xor(v, 16);              // butterfly over the 4 fg groups
                v += __shfl_xor(v, 32);
                lg[n][p] = v * 0.125f - gate[p];     // / sqrt(64)
                mk[n][p] = fmaxf(lg[n][p], 0.f);
            }
        // fg0: logits n=0 | fg1: logits n=1 | fg2: mask+wt n=0 | fg3: mask+wt n=1
        int ns = fg & 1;
        size_t rowb = (size_t)(t0 + ns * 16 + fr) * NEXP;
        f32x4 v0, v1;
        if (fg < 2) {
#pragma unroll
            for (int i = 0; i < 4; ++i) { v0[i] = lg[ns][i]; v1[i] = lg[ns][4 + i]; }
            *reinterpret_cast<f32x4*>(logits_out + rowb) = v0;
            *reinterpret_cast<f32x4*>(logits_out + rowb + 4) = v1;
        } else {
#pragma unroll
            for (int i = 0; i < 4; ++i) { v0[i] = mk[ns][i]; v1[i] = mk[ns][4 + i]; }
            *reinterpret_cast<f32x4*>(mask_out + rowb) = v0;
            *reinterpret_cast<f32x4*>(mask_out + rowb + 4) = v1;
            f32x4 w0, w1v;
#pragma unroll
            for (int i = 0; i < 4; ++i) {
                w0[i]  = (v0[i] > 1e-6f) ? v0[i] : 0.f;
                w1v[i] = (v1[i] > 1e-6f) ? v1[i] : 0.f;
            }
            char* wb = smem + OFF_WT + (wv * 32 + ns * 16 + fr) * 32;
            *reinterpret_cast<f32x4*>(wb) = w0;
            *reinterpret_cast<f32x4*>(wb + 16) = w1v;
        }
    }

    // ---- Phase B prologue: issue W0 DMA, pack X->bf16 under it ----
    stage(0, 0);
    short8 xb[2][2];
#pragma unroll
    for (int n = 0; n < 2; ++n)
#pragma unroll
        for (int kk = 0; kk < 2; ++kk) {
            short8 t;
#pragma unroll
            for (int j = 0; j < 8; ++j) t[j] = (short)f2bf(xv[n][kk][j]);
            xb[n][kk] = t;
        }
    __syncthreads();                                 // W0 + wt table visible

    f32x4 yacc[4][2];
#pragma unroll
    for (int mt = 0; mt < 4; ++mt)
#pragma unroll
        for (int n = 0; n < 2; ++n) yacc[mt][n] = (f32x4){0.f, 0.f, 0.f, 0.f};

    const float* const wtp = reinterpret_cast<const float*>(smem + OFF_WT);

#pragma unroll 1
    for (int p = 0; p < NEXP; ++p) {
        const int cur = p & 1;
        if (p < NEXP - 1) stage(p + 1, cur ^ 1);     // prefetch next expert
        const char* sW1 = smem + (cur << 14);
        const char* sW2 = sW1 + 8192;
        const float wt0 = wtp[(wv * 32 + fr) * 8 + p];        // token n=0 (broadcast)
        const float wt1 = wtp[(wv * 32 + 16 + fr) * 8 + p];   // token n=1

#pragma unroll
        for (int h = 0; h < 2; ++h) {                // o-halves: o in [h*32, h*32+32)
            short8 w1f[2][2];
#pragma unroll
            for (int mtl = 0; mtl < 2; ++mtl)
#pragma unroll
                for (int kk = 0; kk < 2; ++kk)
                    w1f[mtl][kk] = *reinterpret_cast<const short8*>(
                        sW1 + (h * 32 + mtl * 16 + fr) * 128 + ((kk * 64 + fg * 16) ^ sw));
            f32x4 acc1[2][2];
#pragma unroll
            for (int mtl = 0; mtl < 2; ++mtl)
#pragma unroll
                for (int n = 0; n < 2; ++n) acc1[mtl][n] = (f32x4){0.f, 0.f, 0.f, 0.f};
#pragma unroll
            for (int kk = 0; kk < 2; ++kk)
#pragma unroll
                for (int mtl = 0; mtl < 2; ++mtl)
#pragma unroll
                    for (int n = 0; n < 2; ++n)
                        acc1[mtl][n] = __builtin_amdgcn_mfma_f32_16x16x32_bf16(
                            w1f[mtl][kk], xb[n][kk], acc1[mtl][n], 0, 0, 0);

            // silu * wt -> bf16 (GEMM2 B-frag layout, in-register)
            bf16x4 pkB[2][2];
#pragma unroll
            for (int mtl = 0; mtl < 2; ++mtl)
#pragma unroll
                for (int n = 0; n < 2; ++n) {
                    const float wt = n ? wt1 : wt0;
                    bf16x4 t;
#pragma unroll
                    for (int r = 0; r < 4; ++r) {
                        float hd = acc1[mtl][n][r];
                        float s = hd * __builtin_amdgcn_rcpf(1.f + __expf(-hd));
                        t[r] = (short)f2bf(wt * s);
                    }
                    pkB[mtl][n] = t;
                }

            // GEMM2 k-slices mp = 2h, 2h+1 accumulate straight into yacc
#pragma unroll
            for (int mt = 0; mt < 4; ++mt) {
                u32x4 wq = *reinterpret_cast<const u32x4*>(
                    sW2 + (mt * 16 + fr) * 128 + ((fg * 32 + h * 16) ^ sw));
                u32x2 lo2 = {wq[0], wq[1]}, hi2 = {wq[2], wq[3]};
                bf16x4 wlo = __builtin_bit_cast(bf16x4, lo2);
                bf16x4 whi = __builtin_bit_cast(bf16x4, hi2);
#pragma unroll
                for (int n = 0; n < 2; ++n) {
                    yacc[mt][n] = MFMA16(wlo, pkB[0][n], yacc[mt][n]);
                    yacc[mt][n] = MFMA16(whi, pkB[1][n], yacc[mt][n]);
                }
            }
        }
        if (p < NEXP - 1) __syncthreads();           // next W landed; cur reusable
    }

    // ---- y store: lane (d = mt*16+fg*4+r, t = n*16+fr) ----
#pragma unroll
    for (int mt = 0; mt < 4; ++mt)
#pragma unroll
        for (int n = 0; n < 2; ++n) {
            f32x4 v;
#pragma unroll
            for (int r = 0; r < 4; ++r) v[r] = yacc[mt][n][r];
            *reinterpret_cast<f32x4*>(
                y_out + (size_t)(t0 + n * 16 + fr) * DH + mt * 16 + fg * 4) = v;
        }
}

extern "C" void kernel_launch(void* const* d_in, const int* in_sizes, int n_in,
                              void* d_out, int out_size, void* d_ws, size_t ws_size,
                              hipStream_t stream) {
    (void)n_in; (void)out_size; (void)ws_size;
    const float* x     = (const float*)d_in[0];
    const float* proto = (const float*)d_in[1];
    const float* gate  = (const float*)d_in[2];
    const float* w1    = (const float*)d_in[3];
    const float* w2    = (const float*)d_in[4];
    float* y = (float*)d_out;
    const int S = in_sizes[0] / DH;                  // 131072
    float* logits = y + (size_t)S * DH;
    float* mask   = logits + (size_t)S * NEXP;
    unsigned char* wimg = (unsigned char*)d_ws;      // 128 KiB image

    prep_w<<<64, 256, 0, stream>>>(w1, w2, wimg);
    spl_main<<<S / BT, THREADS, 0, stream>>>(x, proto, gate, wimg, y, logits, mask);
}

// Round 6
// 54.480 us; speedup vs baseline: 3.3227x; 1.0627x over previous
//
#include <hip/hip_runtime.h>
#include <hip/hip_bf16.h>

// SparseProtoLinear: S=131072 tokens, D=64, P=8 experts.
// d_out = [y (S*64) | logits (S*8) | mask (S*8)], fp32.
//
// prep_w: fp32 W1/W2 -> bf16 image in d_ws (XOR-swizzled rows; W2 columns
//         permuted [mp|fg|j]->[fg|mp|j] so GEMM2 A-frags read as b128).
// spl_main: 512 blocks x 512 thr (8 waves = 1 CU), 256 tokens/block.
//   Phase A (no DMA in flight): X->reg, fp32 logits/mask, wt->LDS table.
//   Then: whole 128KB W image -> LDS once (global_load_lds), ONE barrier.
//   Expert loop (unroll 1, ZERO barriers): GEMM1 swapped (W1 x X^T,
//   mfma 16x16x32), silu*wt -> bf16 in-register (compiler cvt_pk), GEMM2
//   (mfma 16x16x16) accumulates into yacc. Epilogue: yacc -> LDS ->
//   full-cacheline 1KB/instruction y stores.

typedef __attribute__((ext_vector_type(8))) short short8;
typedef __attribute__((ext_vector_type(4))) short bf16x4;   // HIP owns `short4`
typedef __attribute__((ext_vector_type(4))) float f32x4;
typedef __attribute__((ext_vector_type(4))) unsigned int u32x4;
typedef __attribute__((ext_vector_type(2))) unsigned int u32x2;

#define NEXP 8
#define DH 64
#define BT 256
#define THREADS 512
#define OFF_WT (128 * 1024)
#define LDS_BYTES (128 * 1024 + 8 * 1024)   // W image + 256x8 wt table

__device__ __forceinline__ unsigned int f2bf(float f) {
    unsigned int u = __builtin_bit_cast(unsigned int, f);
    return (u + 0x7fffu + ((u >> 16) & 1u)) >> 16;  // RTNE (prep kernel only)
}
__device__ __forceinline__ short bfc(float f) {     // compiler-lowered convert
    return (short)__bfloat16_as_ushort(__float2bfloat16(f));
}

#if __has_builtin(__builtin_amdgcn_mfma_f32_16x16x16_bf16)
#define MFMA16(a, b, c) __builtin_amdgcn_mfma_f32_16x16x16_bf16(a, b, c, 0, 0, 0)
#else
#define MFMA16(a, b, c) __builtin_amdgcn_mfma_f32_16x16x16bf16_1k(a, b, c, 0, 0, 0)
#endif

typedef const unsigned int __attribute__((address_space(1)))* gas_u32p;
typedef unsigned int __attribute__((address_space(3)))* las_u32p;

// g includes the per-lane offset; lbase is wave-uniform (HW adds lane*16).
__device__ __forceinline__ void glds16(const void* g, void* lbase, int lane) {
#if __has_builtin(__builtin_amdgcn_global_load_lds)
    (void)lane;
    __builtin_amdgcn_global_load_lds((gas_u32p)g, (las_u32p)lbase, 16, 0, 0);
#else
    *reinterpret_cast<u32x4*>(reinterpret_cast<char*>(lbase) + lane * 16) =
        *reinterpret_cast<const u32x4*>(g);
#endif
}

// ---------------- prep: weights -> bf16 swizzled image (128 KiB) ----------------
__global__ void prep_w(const float* __restrict__ w1, const float* __restrict__ w2,
                       unsigned char* __restrict__ ws) {
    int q = blockIdx.x * 256 + threadIdx.x;          // 16384 quads of 4 f32
    int mat = q >> 13;                               // 0=W1, 1=W2
    int p = (q >> 10) & 7;
    int r = (q >> 4) & 63;                           // source row (o for W1, d for W2)
    int dq = q & 15;                                 // source col quad
    const float* src = (mat ? w2 : w1) + (size_t)(((p << 6) + r) << 6) + (dq << 2);
    f32x4 v = *reinterpret_cast<const f32x4*>(src);
    u32x2 pk;
    pk[0] = f2bf(v[0]) | (f2bf(v[1]) << 16);
    pk[1] = f2bf(v[2]) | (f2bf(v[3]) << 16);
    // W1: byte col = dq*8.  W2 col-permute o=[mp|fg|j]->[fg|mp|j]:
    //   mp=dq>>2, fg=dq&3 -> byte col = fg*32 + mp*8.
    int col = mat ? (((dq & 3) << 5) | ((dq >> 2) << 3)) : (dq << 3);
    int off = (p << 14) + (mat << 13) + (r << 7) + (col ^ ((r & 7) << 4));
    *reinterpret_cast<u32x2*>(ws + off) = pk;
}

// ---------------- main fused kernel ----------------
__global__ __launch_bounds__(THREADS, 1)
void spl_main(const float* __restrict__ x, const float* __restrict__ proto,
              const float* __restrict__ gate, const unsigned char* __restrict__ wimg,
              float* __restrict__ y_out, float* __restrict__ logits_out,
              float* __restrict__ mask_out)
{
    extern __shared__ __align__(16) char smem[];     // [0,128K) W | [128K,136K) wt
    const int tid = threadIdx.x;
    const int lane = tid & 63;
    const int wv = __builtin_amdgcn_readfirstlane(tid >> 6);
    const int fr = lane & 15;
    const int fg = (lane >> 4) & 3;
    const int sw = (fr & 7) << 4;
    const int t0 = blockIdx.x * BT + wv * 32;        // wave-local 32 tokens

    // ---- Phase A: X load + logits/mask + wt table (NO DMA in flight) ----
    float xv[2][2][8];
#pragma unroll
    for (int n = 0; n < 2; ++n)
#pragma unroll
        for (int kk = 0; kk < 2; ++kk) {
            const float* g = x + (size_t)(t0 + n * 16 + fr) * DH + kk * 32 + fg * 8;
            f32x4 a = *reinterpret_cast<const f32x4*>(g);
            f32x4 b = *reinterpret_cast<const f32x4*>(g + 4);
#pragma unroll
            for (int i = 0; i < 4; ++i) { xv[n][kk][i] = a[i]; xv[n][kk][4 + i] = b[i]; }
        }
    {
        float dot[2][NEXP];
#pragma unroll
        for (int n = 0; n < 2; ++n)
#pragma unroll
            for (int p = 0; p < NEXP; ++p) dot[n][p] = 0.f;
#pragma unroll
        for (int p = 0; p < NEXP; ++p)
#pragma unroll
            for (int kk = 0; kk < 2; ++kk) {
                const float* pr = proto + p * DH + kk * 32 + fg * 8;
                f32x4 p0 = *reinterpret_cast<const f32x4*>(pr);
                f32x4 p1 = *reinterpret_cast<const f32x4*>(pr + 4);
#pragma unroll
                for (int n = 0; n < 2; ++n)
#pragma unroll
                    for (int i = 0; i < 4; ++i)
                        dot[n][p] += xv[n][kk][i] * p0[i] + xv[n][kk][4 + i] * p1[i];
            }
        float lg[2][NEXP], mk[2][NEXP];
#pragma unroll
        for (int n = 0; n < 2; ++n)
#pragma unroll
            for (int p = 0; p < NEXP; ++p) {
                float v = dot[n][p];
                v += __shfl_xor(v, 16);              // butterfly over the 4 fg groups
                v += __shfl_xor(v, 32);
                lg[n][p] = v * 0.125f - gate[p];     // / sqrt(64)
                mk[n][p] = fmaxf(lg[n][p], 0.f);
            }
        // fg0: logits n=0 | fg1: logits n=1 | fg2: mask+wt n=0 | fg3: mask+wt n=1
        int ns = fg & 1;
        size_t rowb = (size_t)(t0 + ns * 16 + fr) * NEXP;
        f32x4 v0, v1;
        if (fg < 2) {
#pragma unroll
            for (int i = 0; i < 4; ++i) { v0[i] = lg[ns][i]; v1[i] = lg[ns][4 + i]; }
            *reinterpret_cast<f32x4*>(logits_out + rowb) = v0;
            *reinterpret_cast<f32x4*>(logits_out + rowb + 4) = v1;
        } else {
#pragma unroll
            for (int i = 0; i < 4; ++i) { v0[i] = mk[ns][i]; v1[i] = mk[ns][4 + i]; }
            *reinterpret_cast<f32x4*>(mask_out + rowb) = v0;
            *reinterpret_cast<f32x4*>(mask_out + rowb + 4) = v1;
            f32x4 w0, w1v;
#pragma unroll
            for (int i = 0; i < 4; ++i) {
                w0[i]  = (v0[i] > 1e-6f) ? v0[i] : 0.f;
                w1v[i] = (v1[i] > 1e-6f) ? v1[i] : 0.f;
            }
            char* wb = smem + OFF_WT + (wv * 32 + ns * 16 + fr) * 32;
            *reinterpret_cast<f32x4*>(wb) = w0;
            *reinterpret_cast<f32x4*>(wb + 16) = w1v;
        }
    }

    // ---- stage whole 128KB W image (issued after logits phase) ----
#pragma unroll
    for (int i = 0; i < 16; ++i)
        glds16(wimg + i * 8192 + wv * 1024 + lane * 16,
               smem + i * 8192 + wv * 1024, lane);

    // pack X->bf16 under the DMA
    short8 xb[2][2];
#pragma unroll
    for (int n = 0; n < 2; ++n)
#pragma unroll
        for (int kk = 0; kk < 2; ++kk) {
            short8 t;
#pragma unroll
            for (int j = 0; j < 8; ++j) t[j] = bfc(xv[n][kk][j]);
            xb[n][kk] = t;
        }
    __syncthreads();                                 // W + wt table visible

    f32x4 yacc[4][2];
#pragma unroll
    for (int mt = 0; mt < 4; ++mt)
#pragma unroll
        for (int n = 0; n < 2; ++n) yacc[mt][n] = (f32x4){0.f, 0.f, 0.f, 0.f};

    const float* const wtp = reinterpret_cast<const float*>(smem + OFF_WT);

    // ---- expert loop: ZERO barriers, waves free-run ----
#pragma unroll 1
    for (int p = 0; p < NEXP; ++p) {
        const char* sW1 = smem + (p << 14);
        const char* sW2 = sW1 + 8192;
        const float wt0 = wtp[(wv * 32 + fr) * 8 + p];        // token n=0
        const float wt1 = wtp[(wv * 32 + 16 + fr) * 8 + p];   // token n=1

#pragma unroll
        for (int h = 0; h < 2; ++h) {                // o-halves: o in [h*32, h*32+32)
            short8 w1f[2][2];
#pragma unroll
            for (int mtl = 0; mtl < 2; ++mtl)
#pragma unroll
                for (int kk = 0; kk < 2; ++kk)
                    w1f[mtl][kk] = *reinterpret_cast<const short8*>(
                        sW1 + (h * 32 + mtl * 16 + fr) * 128 + ((kk * 64 + fg * 16) ^ sw));
            f32x4 acc1[2][2];
#pragma unroll
            for (int mtl = 0; mtl < 2; ++mtl)
#pragma unroll
                for (int n = 0; n < 2; ++n) acc1[mtl][n] = (f32x4){0.f, 0.f, 0.f, 0.f};
#pragma unroll
            for (int kk = 0; kk < 2; ++kk)
#pragma unroll
                for (int mtl = 0; mtl < 2; ++mtl)
#pragma unroll
                    for (int n = 0; n < 2; ++n)
                        acc1[mtl][n] = __builtin_amdgcn_mfma_f32_16x16x32_bf16(
                            w1f[mtl][kk], xb[n][kk], acc1[mtl][n], 0, 0, 0);

            // silu * wt -> bf16 (GEMM2 B-frag layout, in-register)
            bf16x4 pkB[2][2];
#pragma unroll
            for (int mtl = 0; mtl < 2; ++mtl)
#pragma unroll
                for (int n = 0; n < 2; ++n) {
                    const float wt = n ? wt1 : wt0;
                    bf16x4 t;
#pragma unroll
                    for (int r = 0; r < 4; ++r) {
                        float hd = acc1[mtl][n][r];
                        float s = hd * __builtin_amdgcn_rcpf(1.f + __expf(-hd));
                        t[r] = bfc(wt * s);
                    }
                    pkB[mtl][n] = t;
                }

            // GEMM2 k-slices mp = 2h, 2h+1 accumulate straight into yacc
#pragma unroll
            for (int mt = 0; mt < 4; ++mt) {
                u32x4 wq = *reinterpret_cast<const u32x4*>(
                    sW2 + (mt * 16 + fr) * 128 + ((fg * 32 + h * 16) ^ sw));
                u32x2 lo2 = {wq[0], wq[1]}, hi2 = {wq[2], wq[3]};
                bf16x4 wlo = __builtin_bit_cast(bf16x4, lo2);
                bf16x4 whi = __builtin_bit_cast(bf16x4, hi2);
#pragma unroll
                for (int n = 0; n < 2; ++n) {
                    yacc[mt][n] = MFMA16(wlo, pkB[0][n], yacc[mt][n]);
                    yacc[mt][n] = MFMA16(whi, pkB[1][n], yacc[mt][n]);
                }
            }
        }
    }

    // ---- epilogue: yacc -> LDS (W region dead) -> full-line y stores ----
    __syncthreads();                                 // all waves done with W
    char* const yb = smem + wv * 8192;               // 32 rows x 256B per wave
#pragma unroll
    for (int mt = 0; mt < 4; ++mt)
#pragma unroll
        for (int n = 0; n < 2; ++n) {
            f32x4 v;
#pragma unroll
            for (int r = 0; r < 4; ++r) v[r] = yacc[mt][n][r];
            *reinterpret_cast<f32x4*>(
                yb + (n * 16 + fr) * 256 + ((mt * 64 + fg * 16) ^ sw)) = v;
        }
    __builtin_amdgcn_s_waitcnt(0);                   // lgkm drain (per-wave region)
#pragma unroll
    for (int it = 0; it < 8; ++it) {
        const int r = it * 4 + (lane >> 4);          // row 0..31
        const int cb = (lane & 15) * 16;             // col byte within 256B row
        f32x4 v = *reinterpret_cast<const f32x4*>(yb + r * 256 + (cb ^ ((r & 7) << 4)));
        *reinterpret_cast<f32x4*>(
            reinterpret_cast<char*>(y_out) + (size_t)(t0 + r) * 256 + cb) = v;
    }
}

extern "C" void kernel_launch(void* const* d_in, const int* in_sizes, int n_in,
                              void* d_out, int out_size, void* d_ws, size_t ws_size,
                              hipStream_t stream) {
    (void)n_in; (void)out_size; (void)ws_size;
    const float* x     = (const float*)d_in[0];
    const float* proto = (const float*)d_in[1];
    const float* gate  = (const float*)d_in[2];
    const float* w1    = (const float*)d_in[3];
    const float* w2    = (const float*)d_in[4];
    float* y = (float*)d_out;
    const int S = in_sizes[0] / DH;                  // 131072
    float* logits = y + (size_t)S * DH;
    float* mask   = logits + (size_t)S * NEXP;
    unsigned char* wimg = (unsigned char*)d_ws;      // 128 KiB image

    prep_w<<<64, 256, 0, stream>>>(w1, w2, wimg);
    (void)hipFuncSetAttribute(reinterpret_cast<const void*>(spl_main),
                              hipFuncAttributeMaxDynamicSharedMemorySize, LDS_BYTES);
    spl_main<<<S / BT, THREADS, LDS_BYTES, stream>>>(x, proto, gate, wimg,
                                                     y, logits, mask);
}